// Round 1
// baseline (636.939 us; speedup 1.0000x reference)
//
#include <hip/hip_runtime.h>
#include <hip/hip_bf16.h>

// VQVAE forward, MI355X. fp32 everywhere on the encoder path (argmin-stability).
// Pipeline: k0 prep(weight transpose) | k1 conv1+stats | k2 bn1 | k3 conv2+stats |
// k4 bn2 | k5 preq+VQ(idx,qloss) | k6 P-table+qloss | k6b TT-table | k7 d1=TT-lookup
// (+stats) | k8 bn_d | k9 convT2+tanh from d1.
// enc_b1/enc_b2/dec_b1 are cancelled by training-mode BN -> unused.

#define EPSB 1e-5f

__device__ __forceinline__ float wredf(float v){
#pragma unroll
  for (int m = 32; m >= 1; m >>= 1) v += __shfl_xor(v, m, 64);
  return v;
}

// ---------------- k0: transpose weights into [tap][co] layouts ---------------
__global__ __launch_bounds__(256) void k0_prep(
    const float* __restrict__ w1, const float* __restrict__ w2,
    const float* __restrict__ dw2,
    float* __restrict__ wt1, float* __restrict__ wt2, float* __restrict__ wt9)
{
  const int s = blockIdx.x * 256 + threadIdx.x;
  if (s < 768){ // wt1[tap=ci*16+ky*4+kx][co16]
    int tap = s >> 4, co = s & 15;
    int ci = tap >> 4, ky = (tap >> 2) & 3, kx = tap & 3;
    wt1[s] = w1[((co*3 + ci)*4 + ky)*4 + kx];
  }
  if (s < 16384){ // wt2[tap=ci*16+ky*4+kx][co64]
    int tap = s >> 6, co = s & 63;
    int ci = tap >> 4, ky = (tap >> 2) & 3, kx = tap & 3;
    wt2[s] = w2[((co*16 + ci)*4 + ky)*4 + kx];
  }
  if (s < 768){ // wt9[ky][ci][kx*3+co]  (dec_w2: [ci16][co3][ky][kx])
    int ky = s / 192, rem = s - ky*192, ci = rem / 12, r12 = rem - ci*12;
    int kx = r12 / 3, co = r12 - kx*3;
    wt9[s] = dw2[((ci*3 + co)*4 + ky)*4 + kx];
  }
}

// ---------------- k1: conv1 3->16 s2 p1 on x(32,3,512,512) + stats ----------
__global__ __launch_bounds__(256) void k1_conv1(
    const float* __restrict__ x, const float* __restrict__ wt1,
    float* __restrict__ h1, float* __restrict__ part1)
{
  __shared__ float xt[3*10*516];
  __shared__ float red[128];
  const int b = blockIdx.x, t = threadIdx.x;
  const int n = b >> 6, oy0 = (b & 63) << 2;
  const int iy0 = 2*oy0 - 1;
  for (int s = t; s < 15420; s += 256){
    int ci = s / 5140, r2 = s - ci*5140, rr = r2 / 514, c = r2 - rr*514;
    int iy = iy0 + rr, ix = c - 1;
    float v = 0.f;
    if ((unsigned)iy < 512u && (unsigned)ix < 512u)
      v = x[((size_t)(n*3 + ci) << 18) + (iy << 9) + ix];
    xt[(ci*10 + rr)*516 + c] = v;
  }
  __syncthreads();
  const int row = t >> 6, l = t & 63;
  float acc[4][16];
#pragma unroll
  for (int j = 0; j < 4; j++)
#pragma unroll
    for (int q = 0; q < 16; q++) acc[j][q] = 0.f;

  for (int ci = 0; ci < 3; ci++){
    for (int ky = 0; ky < 4; ky++){
      const float* xrow = &xt[(ci*10 + 2*row + ky)*516];
#pragma unroll
      for (int kx = 0; kx < 4; kx++){
        const float* wp = &wt1[(((ci*4 + ky)*4 + kx) << 4)]; // uniform -> s_load
        float wv[16];
#pragma unroll
        for (int q = 0; q < 16; q++) wv[q] = wp[q];
#pragma unroll
        for (int j = 0; j < 4; j++){
          float v = xrow[2*(l + 64*j) + kx];
#pragma unroll
          for (int q = 0; q < 16; q++) acc[j][q] = fmaf(v, wv[q], acc[j][q]);
        }
      }
    }
  }
  const int oy = oy0 + row;
  float s[16], ss[16];
#pragma unroll
  for (int q = 0; q < 16; q++){ s[q] = 0.f; ss[q] = 0.f; }
#pragma unroll
  for (int j = 0; j < 4; j++){
    int ox = l + 64*j;
    size_t base = ((size_t)(n*16) << 16) + (oy << 8) + ox;
#pragma unroll
    for (int q = 0; q < 16; q++){
      float v = acc[j][q];
      h1[base + ((size_t)q << 16)] = v;
      s[q] += v; ss[q] += v*v;
    }
  }
#pragma unroll
  for (int q = 0; q < 16; q++){ s[q] = wredf(s[q]); ss[q] = wredf(ss[q]); }
  if (l == 0){
#pragma unroll
    for (int q = 0; q < 16; q++){ red[row*32 + q] = s[q]; red[row*32 + 16 + q] = ss[q]; }
  }
  __syncthreads();
  if (t < 32) part1[b*32 + t] = red[t] + red[32+t] + red[64+t] + red[96+t];
}

// ---------------- reduce partials -> scale/shift (BN) ------------------------
__global__ __launch_bounds__(256) void k_stats(
    const float* __restrict__ part, int nslots, int slotstride, int grouped,
    const float* __restrict__ g, const float* __restrict__ be,
    float* __restrict__ scale, float* __restrict__ shift, float Ninv)
{
  const int c = blockIdx.x, t = threadIdx.x;
  const int off = grouped ? ((c >> 4) << 5) : 0;
  const int ci = grouped ? (c & 15) : c;
  float S = 0.f, SS = 0.f;
  for (int q = t; q < nslots; q += 256){
    const float* pp = &part[(size_t)q * slotstride + off];
    S += pp[ci]; SS += pp[16 + ci];
  }
  S = wredf(S); SS = wredf(SS);
  __shared__ float sb[8];
  if ((t & 63) == 0){ sb[t >> 6] = S; sb[4 + (t >> 6)] = SS; }
  __syncthreads();
  if (t == 0){
    float Sv = sb[0]+sb[1]+sb[2]+sb[3], SSv = sb[4]+sb[5]+sb[6]+sb[7];
    float m = Sv * Ninv;
    float var = SSv * Ninv - m*m;
    float sc = g[c] * rsqrtf(var + EPSB);
    scale[c] = sc;
    shift[c] = be[c] - m * sc;
  }
}

// ---------------- k3: conv2 16->64 s2 p1 with fused bn1+relu, + stats --------
__global__ __launch_bounds__(256) void k3_conv2(
    const float* __restrict__ h1, const float* __restrict__ wt2,
    const float* __restrict__ misc, float* __restrict__ h2, float* __restrict__ part2)
{
  __shared__ float a1t[4*6*260];
  __shared__ float s1[16], t1[16];
  __shared__ float red[128];
  const int b = blockIdx.x, t = threadIdx.x;
  const int n = b >> 6, oy0 = (b & 63) << 1;
  if (t < 16){ s1[t] = misc[t]; t1[t] = misc[16 + t]; }
  const int cg = t >> 6, pg = t & 63, oyr = pg >> 5, lx = pg & 31;
  const int cgu = __builtin_amdgcn_readfirstlane(cg);
  const int oy = oy0 + oyr, iy0 = 2*oy0 - 1;
  float acc[4][16];
#pragma unroll
  for (int j = 0; j < 4; j++)
#pragma unroll
    for (int q = 0; q < 16; q++) acc[j][q] = 0.f;

  for (int cc = 0; cc < 4; cc++){
    __syncthreads();
    for (int s = t; s < 6192; s += 256){
      int ci = s / 1548, r2 = s - ci*1548, rr = r2 / 258, c = r2 - rr*258;
      int iy = iy0 + rr, ix = c - 1;
      float v = 0.f;
      if ((unsigned)iy < 256u && (unsigned)ix < 256u){
        int gci = cc*4 + ci;
        float raw = h1[((size_t)(n*16 + gci) << 16) + (iy << 8) + ix];
        v = fmaxf(fmaf(raw, s1[gci], t1[gci]), 0.f);
      }
      a1t[(ci*6 + rr)*260 + c] = v;
    }
    __syncthreads();
    for (int cl = 0; cl < 4; cl++){
      for (int ky = 0; ky < 4; ky++){
        const float* arow = &a1t[(cl*6 + 2*oyr + ky)*260];
#pragma unroll
        for (int kx = 0; kx < 4; kx++){
          const float* wp = &wt2[(size_t)cc*4096 + (((cl*16 + ky*4 + kx)) << 6) + (cgu << 4)];
          float wv[16];
#pragma unroll
          for (int q = 0; q < 16; q++) wv[q] = wp[q];   // uniform -> s_load
#pragma unroll
          for (int j = 0; j < 4; j++){
            float v = arow[2*(lx + 32*j) + kx];
#pragma unroll
            for (int q = 0; q < 16; q++) acc[j][q] = fmaf(v, wv[q], acc[j][q]);
          }
        }
      }
    }
  }
  float s[16], ss[16];
#pragma unroll
  for (int q = 0; q < 16; q++){ s[q] = 0.f; ss[q] = 0.f; }
  const int cob = cg << 4;
#pragma unroll
  for (int j = 0; j < 4; j++){
    int ox = lx + 32*j;
    size_t base = ((size_t)(n*64 + cob) << 14) + (oy << 7) + ox;
#pragma unroll
    for (int q = 0; q < 16; q++){
      float v = acc[j][q];
      h2[base + ((size_t)q << 14)] = v;
      s[q] += v; ss[q] += v*v;
    }
  }
#pragma unroll
  for (int q = 0; q < 16; q++){ s[q] = wredf(s[q]); ss[q] = wredf(ss[q]); }
  if (pg == 0){
#pragma unroll
    for (int q = 0; q < 16; q++){ red[cg*32 + q] = s[q]; red[cg*32 + 16 + q] = ss[q]; }
  }
  __syncthreads();
  if (t < 128) part2[b*128 + t] = red[t];
}

// ---------------- k5: preq(1x1,bn2+relu fused) + VQ argmin + qloss + idx -----
__global__ __launch_bounds__(256) void k5_vq(
    const float* __restrict__ h2, const float* __restrict__ misc,
    const float* __restrict__ pw, const float* __restrict__ pb,
    const float* __restrict__ emb, unsigned char* __restrict__ idxb,
    float* __restrict__ qsum)
{
  __shared__ float s2[64], t2[64], w0s[64], w1s[64];
  __shared__ float eb[4];
  const int t = threadIdx.x;
  if (t < 64){ s2[t] = misc[32 + t]; t2[t] = misc[96 + t]; w0s[t] = pw[t]; w1s[t] = pw[64 + t]; }
  __syncthreads();
  const int p = blockIdx.x * 256 + t;
  const int n = p >> 14, pos = p & 16383;
  const float* hp = h2 + ((size_t)n << 20) + pos;
  float q0 = pb[0], q1 = pb[1];
  for (int c = 0; c < 64; c++){
    float v = fmaxf(fmaf(hp[(size_t)c << 14], s2[c], t2[c]), 0.f);
    q0 = fmaf(v, w0s[c], q0);
    q1 = fmaf(v, w1s[c], q1);
  }
  float dx0 = q0-emb[0], dy0 = q1-emb[1];
  float dx1 = q0-emb[2], dy1 = q1-emb[3];
  float dx2 = q0-emb[4], dy2 = q1-emb[5];
  float d0 = dx0*dx0+dy0*dy0, d1 = dx1*dx1+dy1*dy1, d2 = dx2*dx2+dy2*dy2;
  int bi = 0; float db = d0;
  if (d1 < db){ db = d1; bi = 1; }
  if (d2 < db){ db = d2; bi = 2; }
  idxb[p] = (unsigned char)bi;
  float e = wredf(db);
  if ((t & 63) == 0) eb[t >> 6] = e;
  __syncthreads();
  if (t == 0) atomicAdd(qsum, eb[0]+eb[1]+eb[2]+eb[3]);
}

// ---------------- k6: P table (postq of each code) + final qloss -------------
__global__ __launch_bounds__(256) void k6_tables(
    const float* __restrict__ postq_w, const float* __restrict__ postq_b,
    const float* __restrict__ emb, float* __restrict__ misc, float* __restrict__ qout)
{
  const int t = threadIdx.x;
  if (t < 192){
    int i = t >> 6, ci = t & 63;
    misc[200 + t] = fmaf(postq_w[ci*2], emb[i*2],
                    fmaf(postq_w[ci*2+1], emb[i*2+1], postq_b[ci]));
  }
  if (t == 192) qout[0] = 1.2f * misc[192] * (1.0f/1048576.0f); // (1+0.2)*mean
}

// ---------------- k6b: TT[i][ky][kx][oc] = sum_ci dec_w1 * P ----------------
__global__ __launch_bounds__(64) void k6b_tt(
    const float* __restrict__ dw1, float* __restrict__ misc)
{
  const int e = blockIdx.x;                 // i*256 + (ky*4+kx)*16 + oc
  const int i = e >> 8, rem = e & 255;
  const int kykx = rem >> 4, oc = rem & 15;
  const int ky = kykx >> 2, kx = kykx & 3;
  const int l = threadIdx.x;                // ci (0..63)
  float v = dw1[((l*16 + oc)*4 + ky)*4 + kx] * misc[200 + i*64 + l];
  v = wredf(v);
  if (l == 0) misc[400 + i*260 + rem] = v;  // stride 260: bank-conflict pad
}

// d1raw at (iy,ix): sum of <=4 TT entries indexed by idx map (convT1 collapsed)
__device__ __forceinline__ void d1_accum(const unsigned char* __restrict__ ib,
    int iy, int ix, const float* __restrict__ tt, float* __restrict__ d)
{
  const int py = (iy + 1) & 1, px = (ix + 1) & 1;
#pragma unroll
  for (int kyi = 0; kyi < 2; kyi++){
    int ky = py + 2*kyi, jy = (iy + 1 - ky) >> 1;
    if ((unsigned)jy < 128u){
#pragma unroll
      for (int kxi = 0; kxi < 2; kxi++){
        int kx = px + 2*kxi, jx = (ix + 1 - kx) >> 1;
        if ((unsigned)jx < 128u){
          const float* tb = &tt[(int)ib[(jy << 7) + jx]*260 + (((ky << 2) + kx) << 4)];
#pragma unroll
          for (int q = 0; q < 16; q++) d[q] += tb[q];
        }
      }
    }
  }
}

// ---------------- k7: materialize d1raw (convT1 via TT) + stats --------------
__global__ __launch_bounds__(256) void k7_d1(
    const unsigned char* __restrict__ idxb, const float* __restrict__ misc,
    float* __restrict__ d1, float* __restrict__ partd)
{
  __shared__ float tt[780];
  __shared__ float red[128];
  const int b = blockIdx.x, t = threadIdx.x;
  for (int s = t; s < 780; s += 256) tt[s] = misc[400 + s];
  __syncthreads();
  const int n = b >> 6, row = t >> 6, l = t & 63;
  const int oy = ((b & 63) << 2) + row;
  const unsigned char* ib = idxb + (n << 14);
  float s[16], ss[16];
#pragma unroll
  for (int q = 0; q < 16; q++){ s[q] = 0.f; ss[q] = 0.f; }
#pragma unroll
  for (int j = 0; j < 4; j++){
    int ox = l + 64*j;
    float d[16];
#pragma unroll
    for (int q = 0; q < 16; q++) d[q] = 0.f;
    d1_accum(ib, oy, ox, tt, d);
    size_t base = ((size_t)(n*16) << 16) + (oy << 8) + ox;
#pragma unroll
    for (int q = 0; q < 16; q++){
      d1[base + ((size_t)q << 16)] = d[q];
      s[q] += d[q]; ss[q] += d[q]*d[q];
    }
  }
#pragma unroll
  for (int q = 0; q < 16; q++){ s[q] = wredf(s[q]); ss[q] = wredf(ss[q]); }
  if (l == 0){
#pragma unroll
    for (int q = 0; q < 16; q++){ red[row*32 + q] = s[q]; red[row*32 + 16 + q] = ss[q]; }
  }
  __syncthreads();
  if (t < 32) partd[b*32 + t] = red[t] + red[32+t] + red[64+t] + red[96+t];
}

// ---------------- k9: convT2 16->3 with fused bn_d+relu on d1, + tanh --------
__global__ __launch_bounds__(256) void k9_dec(
    const float* __restrict__ d1, const float* __restrict__ misc,
    const float* __restrict__ wt9, const float* __restrict__ db2,
    float* __restrict__ out)
{
  __shared__ float sd[16], sh[16];
  const int b = blockIdx.x, t = threadIdx.x;
  const int n = b >> 7, G = b & 127;
  if (t < 16){ sd[t] = misc[160 + t]; sh[t] = misc[176 + t]; }
  __syncthreads();
  const int rowq = t >> 6, u = t & 63, m0 = u << 2;
  const int oy2 = (G << 2) + rowq;
  const int py = __builtin_amdgcn_readfirstlane((oy2 + 1) & 1);
  float acc[2][4][3];
#pragma unroll
  for (int p2 = 0; p2 < 2; p2++)
#pragma unroll
    for (int e = 0; e < 4; e++)
#pragma unroll
      for (int c = 0; c < 3; c++) acc[p2][e][c] = 0.f;

#pragma unroll
  for (int kyi = 0; kyi < 2; kyi++){
    const int ky = py + 2*kyi;
    const int iy = (oy2 + 1 - ky) >> 1;
    if ((unsigned)iy < 256u){
      const float* drow = d1 + ((size_t)(n*16) << 16) + (iy << 8);
      for (int ci = 0; ci < 16; ci++){
        const float* wp = &wt9[(ky*16 + ci)*12];  // uniform -> s_load
        float w[12];
#pragma unroll
        for (int q = 0; q < 12; q++) w[q] = wp[q];
        const float* dr = drow + ((size_t)ci << 16);
        float4 vm = *(const float4*)(dr + m0);
        float lm = (m0 > 0)       ? dr[m0 - 1] : 0.f;
        float rm = (m0 + 4 < 256) ? dr[m0 + 4] : 0.f;
        float sv = sd[ci], tv = sh[ci];
        float a[6];
        a[0] = (m0 > 0)       ? fmaxf(fmaf(lm,   sv, tv), 0.f) : 0.f;
        a[1] = fmaxf(fmaf(vm.x, sv, tv), 0.f);
        a[2] = fmaxf(fmaf(vm.y, sv, tv), 0.f);
        a[3] = fmaxf(fmaf(vm.z, sv, tv), 0.f);
        a[4] = fmaxf(fmaf(vm.w, sv, tv), 0.f);
        a[5] = (m0 + 4 < 256) ? fmaxf(fmaf(rm,   sv, tv), 0.f) : 0.f;
#pragma unroll
        for (int e = 0; e < 4; e++){
          float vmm = a[e], v0m = a[e+1], vp1 = a[e+2];
          // kx=0 par1 uses ix=m+1 ; kx=1 par0 ix=m ; kx=2 par1 ix=m ; kx=3 par0 ix=m-1
          acc[1][e][0] = fmaf(vp1, w[0], acc[1][e][0]);
          acc[1][e][1] = fmaf(vp1, w[1], acc[1][e][1]);
          acc[1][e][2] = fmaf(vp1, w[2], acc[1][e][2]);
          acc[0][e][0] = fmaf(v0m, w[3], acc[0][e][0]);
          acc[0][e][1] = fmaf(v0m, w[4], acc[0][e][1]);
          acc[0][e][2] = fmaf(v0m, w[5], acc[0][e][2]);
          acc[1][e][0] = fmaf(v0m, w[6], acc[1][e][0]);
          acc[1][e][1] = fmaf(v0m, w[7], acc[1][e][1]);
          acc[1][e][2] = fmaf(v0m, w[8], acc[1][e][2]);
          acc[0][e][0] = fmaf(vmm, w[9], acc[0][e][0]);
          acc[0][e][1] = fmaf(vmm, w[10], acc[0][e][1]);
          acc[0][e][2] = fmaf(vmm, w[11], acc[0][e][2]);
        }
      }
    }
  }
  const float b0 = db2[0], b1 = db2[1], b2 = db2[2];
#pragma unroll
  for (int e = 0; e < 4; e++){
    int m = m0 + e;
    size_t base = ((size_t)(n*3) << 18) + (oy2 << 9) + 2*m;
    float2 o0 = make_float2(tanhf(acc[0][e][0] + b0), tanhf(acc[1][e][0] + b0));
    float2 o1 = make_float2(tanhf(acc[0][e][1] + b1), tanhf(acc[1][e][1] + b1));
    float2 o2 = make_float2(tanhf(acc[0][e][2] + b2), tanhf(acc[1][e][2] + b2));
    *(float2*)&out[base]              = o0;
    *(float2*)&out[base + (1 << 18)]  = o1;
    *(float2*)&out[base + (2 << 18)]  = o2;
  }
}

// ---------------------------------------------------------------------------
extern "C" void kernel_launch(void* const* d_in, const int* in_sizes, int n_in,
                              void* d_out, int out_size, void* d_ws, size_t ws_size,
                              hipStream_t stream)
{
  (void)in_sizes; (void)n_in; (void)out_size;
  const float* x       = (const float*)d_in[0];
  const float* enc_w1  = (const float*)d_in[1];
  const float* enc_g1  = (const float*)d_in[3];
  const float* enc_be1 = (const float*)d_in[4];
  const float* enc_w2  = (const float*)d_in[5];
  const float* enc_g2  = (const float*)d_in[7];
  const float* enc_be2 = (const float*)d_in[8];
  const float* preq_w  = (const float*)d_in[9];
  const float* preq_b  = (const float*)d_in[10];
  const float* emb     = (const float*)d_in[11];
  const float* postq_w = (const float*)d_in[12];
  const float* postq_b = (const float*)d_in[13];
  const float* dec_w1  = (const float*)d_in[14];
  const float* dec_g1  = (const float*)d_in[16];
  const float* dec_be1 = (const float*)d_in[17];
  const float* dec_w2  = (const float*)d_in[18];
  const float* dec_b2  = (const float*)d_in[19];
  float* out = (float*)d_out;
  char*  ws  = (char*)d_ws;

  // big fp32 intermediates (h1 region is reused for d1 after k3/k5)
  float* h1 = (float*)ws;                         // 134217728 B  (also d1)
  float* h2 = (float*)(ws + 134217728);           // 134217728 B
  // extras at the tail of ws
  size_t ebase = (ws_size - 4194304) & ~(size_t)255;
  unsigned char* idxb = (unsigned char*)(ws + ebase);            // 524288 B
  float* part1 = (float*)(ws + ebase + 524288);                  // <=1 MB
  float* part2 = (float*)(ws + ebase + 1572864);                 // 1 MB
  float* partd = (float*)(ws + ebase + 2621440);                 // <=1 MB
  float* misc  = (float*)(ws + ebase + 3670016);                 // 2048 f
  float* wt1   = (float*)(ws + ebase + 3678208);                 // 768 f
  float* wt2   = (float*)(ws + ebase + 3681280);                 // 16384 f
  float* wt9   = (float*)(ws + ebase + 3746816);                 // 768 f

  k0_prep<<<64, 256, 0, stream>>>(enc_w1, enc_w2, dec_w2, wt1, wt2, wt9);
  hipMemsetAsync(misc + 192, 0, 4, stream);                      // qloss accum

  k1_conv1<<<2048, 256, 0, stream>>>(x, wt1, h1, part1);
  k_stats<<<16, 256, 0, stream>>>(part1, 2048, 32, 0, enc_g1, enc_be1,
                                  misc + 0, misc + 16, 1.f/2097152.f);
  k3_conv2<<<2048, 256, 0, stream>>>(h1, wt2, misc, h2, part2);
  k_stats<<<64, 256, 0, stream>>>(part2, 2048, 128, 1, enc_g2, enc_be2,
                                  misc + 32, misc + 96, 1.f/524288.f);
  k5_vq<<<2048, 256, 0, stream>>>(h2, misc, preq_w, preq_b, emb, idxb, misc + 192);
  k6_tables<<<1, 256, 0, stream>>>(postq_w, postq_b, emb, misc, out + 25165824);
  k6b_tt<<<768, 64, 0, stream>>>(dec_w1, misc);
  k7_d1<<<2048, 256, 0, stream>>>(idxb, misc, h1 /*d1 reuses h1*/, partd);
  k_stats<<<16, 256, 0, stream>>>(partd, 2048, 32, 0, dec_g1, dec_be1,
                                  misc + 160, misc + 176, 1.f/2097152.f);
  k9_dec<<<4096, 256, 0, stream>>>(h1 /*d1*/, misc, wt9, dec_b2, out);
}